// Round 5
// baseline (421.661 us; speedup 1.0000x reference)
//
#include <hip/hip_runtime.h>

// Problem constants (fixed by the reference)
#define KS   5      // kernel size
#define DIL  2      // dilation
#define PAD  4      // (KS/2)*DIL
#define B_   4
#define C_   32
#define P_   8
#define OUTC 24     // DYNAMIC_SIZE
#define H_   512
#define W_   512
#define HW   (H_ * W_)
#define NP   (P_ + OUTC)   // 32 staged planes: 8 guide then 24 data
#define LROW 528           // LDS row: [0..3] pad | [4..515] data | [516..527] pad/slack

typedef float4 f4;

// window shuffle: floats (a.z, a.w, b.x, b.y) — tap at +2 offset across chunks
__device__ __forceinline__ f4 s2(const f4 a, const f4 b) {
    return make_float4(a.z, a.w, b.x, b.y);
}

// v5: one block (128 thr) = one row; 4 px/thread. Per plane the thread's 25
// dilated taps all live in a 12-float window = 3 aligned ds_read_b128 per
// row-set (vs 25 ds_read_b64 at 2 px/thread): 1.7x fewer LDS bytes, and LDS
// data throughput (~85 B/cy/CU, m134) is the measured bottleneck of v4.
// v3's poison removed: no NT stores, no indexed local arrays, compute placed
// BEFORE the commit/vmcnt wait so staging latency hides under tap math.
__global__ __launch_bounds__(128, 3)
void bilateral_w4(const float* __restrict__ inp,   // (B, C, H, W)
                  const float* __restrict__ par,   // (B, P, H, W)
                  float* __restrict__ out)         // (B, OUTC, H, W)
{
    __shared__ float lds[2][KS][LROW];             // 21120 B, double-buffered

    // XCD-aware bijective swizzle (2048 % 8 == 0): each XCD owns 256
    // consecutive rows -> dy-overlap re-reads hit its own L2.
    const int nwg = gridDim.x;                     // 2048
    const int bid = blockIdx.x;
    const int sb  = (bid & 7) * (nwg >> 3) + (bid >> 3);
    const int b = sb >> 9;                         // 512 rows per image
    const int y = sb & (H_ - 1);

    const int u  = threadIdx.x;                    // 0..127
    const int x0 = u << 2;                         // 4 px per thread

    const float* __restrict__ parb = par + (size_t)b * P_ * HW;
    const float* __restrict__ inpb = inp + (size_t)b * C_ * HW;
    float* __restrict__ outb       = out + (size_t)b * OUTC * HW;

    // per-dy clamped row offsets + validity — wave-uniform (SGPR)
    int  rowoff[KS];
    bool rowok[KS];
#pragma unroll
    for (int d = 0; d < KS; ++d) {
        const int yy = y + d * DIL - PAD;
        rowok[d]  = (yy >= 0) & (yy < H_);
        rowoff[d] = min(max(yy, 0), H_ - 1) * W_;
    }

    // zero the pad columns of BOTH buffers once (masked taps read them;
    // they feed only zero-weight taps so they just need to be finite)
    if (u < 8) {
        const int bi = u >> 2, col = u & 3;
#pragma unroll
        for (int r = 0; r < KS; ++r) {
            lds[bi][r][col] = 0.f;
            lds[bi][r][516 + col] = 0.f;
        }
    }

    // ---- staging: issue loads early (regs), commit to LDS late ----
    f4 stg[KS];
    auto issue = [&](int t) {                      // t = plane index 0..NP-1
        const float* pl = (t < P_) ? (parb + (size_t)t * HW)
                                   : (inpb + (size_t)(t - P_) * HW);
#pragma unroll
        for (int r = 0; r < KS; ++r)
            stg[r] = *(const f4*)(pl + rowoff[r] + x0);   // 1 KiB/wave/instr
    };
    auto commit = [&](int bi) {
#pragma unroll
        for (int r = 0; r < KS; ++r)
            *(f4*)&lds[bi][r][4 + x0] = stg[r];
    };

    // ---- wd: d2 accumulator now, weights later (in-place; single array) ----
    // init: 0 for valid taps, BIG for invalid (exp -> exactly 0)
    f4 wd[KS * KS];
#pragma unroll
    for (int d = 0; d < KS; ++d) {
#pragma unroll
        for (int e = 0; e < KS; ++e) {
            const int xb = x0 + e * DIL - PAD;
            f4 v;
            v.x = (rowok[d] && (xb + 0 >= 0) && (xb + 0 < W_)) ? 0.f : 1e5f;
            v.y = (rowok[d] && (xb + 1 >= 0) && (xb + 1 < W_)) ? 0.f : 1e5f;
            v.z = (rowok[d] && (xb + 2 >= 0) && (xb + 2 < W_)) ? 0.f : 1e5f;
            v.w = (rowok[d] && (xb + 3 >= 0) && (xb + 3 < W_)) ? 0.f : 1e5f;
            wd[d * KS + e] = v;
        }
    }

#define WACC(t_, T_) do {                                   \
        float dx_;                                          \
        dx_ = pc.x - (T_).x; wd[t_].x += dx_ * dx_;         \
        dx_ = pc.y - (T_).y; wd[t_].y += dx_ * dx_;         \
        dx_ = pc.z - (T_).z; wd[t_].z += dx_ * dx_;         \
        dx_ = pc.w - (T_).w; wd[t_].w += dx_ * dx_;         \
    } while (0)

#define CACC(t_, T_) do {                                   \
        acc.x += wd[t_].x * (T_).x;                         \
        acc.y += wd[t_].y * (T_).y;                         \
        acc.z += wd[t_].z * (T_).z;                         \
        acc.w += wd[t_].w * (T_).w;                         \
    } while (0)

    // ---- pipeline prologue ----
    issue(0); commit(0); issue(1);

    // ---- weight phase: 8 guide planes, one barrier per plane ----
#pragma unroll 1
    for (int t = 0; t < P_; ++t) {
        __syncthreads();                 // buf[t&1] committed; other buf free
        const int bi = t & 1;

        // row d=2 first: its middle chunk IS the center params pc
        const f4 r2c0 = *(const f4*)&lds[bi][2][x0];
        const f4 r2c1 = *(const f4*)&lds[bi][2][x0 + 4];
        const f4 r2c2 = *(const f4*)&lds[bi][2][x0 + 8];
        const f4 pc = r2c1;
        {
            const f4 t1 = s2(r2c0, r2c1), t3 = s2(r2c1, r2c2);
            WACC(2 * KS + 0, r2c0);
            WACC(2 * KS + 1, t1);
            /* (d=2,e=2) is the center tap: d2 stays 0 */
            WACC(2 * KS + 3, t3);
            WACC(2 * KS + 4, r2c2);
        }
#pragma unroll
        for (int dd = 0; dd < 4; ++dd) {
            const int d = (dd < 2) ? dd : dd + 1;            // 0,1,3,4
            const f4 c0 = *(const f4*)&lds[bi][d][x0];
            const f4 c1 = *(const f4*)&lds[bi][d][x0 + 4];
            const f4 c2 = *(const f4*)&lds[bi][d][x0 + 8];
            const f4 t1 = s2(c0, c1), t3 = s2(c1, c2);
            WACC(d * KS + 0, c0);
            WACC(d * KS + 1, t1);
            WACC(d * KS + 2, c1);
            WACC(d * KS + 3, t3);
            WACC(d * KS + 4, c2);
        }

        // commit next plane AFTER compute: its vmcnt wait hides under tap math
        commit((t + 1) & 1);
        issue(t + 2);                    // planes 2..9 (seam into data)
    }

    // ---- exp in place; fold normalization into the weights ----
    {
        float sx = 0.f, sy = 0.f, sz = 0.f, sw = 0.f;
#pragma unroll
        for (int q = 0; q < KS * KS; ++q) {
            wd[q].x = __expf(-wd[q].x);
            wd[q].y = __expf(-wd[q].y);
            wd[q].z = __expf(-wd[q].z);
            wd[q].w = __expf(-wd[q].w);
            sx += wd[q].x; sy += wd[q].y; sz += wd[q].z; sw += wd[q].w;
        }
        const float ivx = 1.f / (sx + 1e-8f);
        const float ivy = 1.f / (sy + 1e-8f);
        const float ivz = 1.f / (sz + 1e-8f);
        const float ivw = 1.f / (sw + 1e-8f);
#pragma unroll
        for (int q = 0; q < KS * KS; ++q) {
            wd[q].x *= ivx; wd[q].y *= ivy; wd[q].z *= ivz; wd[q].w *= ivw;
        }
    }

    // ---- channel phase: 24 data channels ----
    const size_t obase = (size_t)y * W_ + x0;
#pragma unroll 1
    for (int t = P_; t < NP; ++t) {
        __syncthreads();
        const int bi = t & 1;
        f4 acc = make_float4(0.f, 0.f, 0.f, 0.f);
#pragma unroll
        for (int d = 0; d < KS; ++d) {
            const f4 c0 = *(const f4*)&lds[bi][d][x0];
            const f4 c1 = *(const f4*)&lds[bi][d][x0 + 4];
            const f4 c2 = *(const f4*)&lds[bi][d][x0 + 8];
            const f4 t1 = s2(c0, c1), t3 = s2(c1, c2);
            CACC(d * KS + 0, c0);
            CACC(d * KS + 1, t1);
            CACC(d * KS + 2, c1);
            CACC(d * KS + 3, t3);
            CACC(d * KS + 4, c2);
        }
        *(f4*)(outb + (size_t)(t - P_) * HW + obase) = acc;  // plain store

        if (t + 1 < NP) {
            commit((t + 1) & 1);
            if (t + 2 < NP) issue(t + 2);
        }
    }
#undef WACC
#undef CACC
}

extern "C" void kernel_launch(void* const* d_in, const int* in_sizes, int n_in,
                              void* d_out, int out_size, void* d_ws, size_t ws_size,
                              hipStream_t stream) {
    const float* inp = (const float*)d_in[0];   // (4,32,512,512) fp32
    const float* par = (const float*)d_in[1];   // (4,8,512,512) fp32
    float* out = (float*)d_out;                 // (4,24,512,512) fp32

    dim3 block(128);
    dim3 grid(B_ * H_);                         // 2048 blocks: one row each
    bilateral_w4<<<grid, block, 0, stream>>>(inp, par, out);
}